// Round 2
// baseline (321.120 us; speedup 1.0000x reference)
//
#include <hip/hip_runtime.h>

// Problem constants
#define HW_   36864      // 192*192
#define WI    192
#define HT    192
#define CIN   128
#define DK    256        // == D_V
#define NH    8
#define DKH   32         // channels per head
// TEMPER = 16 -> scale 1/16 = 0.0625

static __device__ __forceinline__ float b2f(unsigned short u) {
    union { unsigned int i; float f; } x; x.i = ((unsigned int)u) << 16; return x.f;
}
static __device__ __forceinline__ unsigned short f2b(float f) {
    union { float f; unsigned int i; } x; x.f = f;
    unsigned int r = x.i + 0x7FFFu + ((x.i >> 16) & 1u);   // round-nearest-even
    return (unsigned short)(r >> 16);
}

// ---------------------------------------------------------------------------
// Kernel D: on-device input-dtype detection. Interpret x as fp32 words.
// fp32 N(0,1) data -> exponent field ~[96,160]. bf16 pairs packed in a word ->
// exponent field comes from the high bf16's exp bits -> ~[236,255]. Count
// plausible-fp32 words; majority vote -> flag (1 = fp32 inputs, 0 = bf16).
// ---------------------------------------------------------------------------
__global__ __launch_bounds__(256) void detect_kernel(
    const unsigned int* __restrict__ xw, int* __restrict__ flag)
{
    __shared__ int sh[256];
    int t = threadIdx.x;
    int cnt = 0;
    for (int i = t; i < 4096; i += 256) {
        unsigned int w = xw[i];
        unsigned int e = (w >> 23) & 0xFF;
        if (e >= 96 && e <= 160) cnt++;
    }
    sh[t] = cnt;
    __syncthreads();
    for (int s = 128; s > 0; s >>= 1) {
        if (t < s) sh[t] += sh[t + s];
        __syncthreads();
    }
    if (t == 0) *flag = (sh[0] > 2048) ? 1 : 0;
}

// ---------------------------------------------------------------------------
// Kernel 0: weights -> fp32 in workspace (uniform-indexed weight reads in the
// projection become scalar s_loads). wf layout: [3][256][128] (q, k, v).
// ---------------------------------------------------------------------------
__global__ __launch_bounds__(256) void convw_kernel(
    const void* __restrict__ wq,
    const void* __restrict__ wk,
    const void* __restrict__ wv,
    const int* __restrict__ flag,
    float* __restrict__ wf)
{
    int i = blockIdx.x * 256 + threadIdx.x;      // 3*32768 = 98304 total
    int which = i >> 15;
    int idx   = i & 32767;
    const void* s = (which == 0) ? wq : ((which == 1) ? wk : wv);
    if (*flag) {
        wf[i] = ((const float*)s)[idx];
    } else {
        wf[i] = b2f(((const unsigned short*)s)[idx]);
    }
}

// ---------------------------------------------------------------------------
// Kernel 1: projection. Per pixel: q,k,v for d in [d0,d0+64) (d0 uniform from
// blockIdx.y); per-head S = sum q*k; vbuf = bf16(v). Block = 192 threads = one
// image row. x staged transposed in LDS as bf16 (converted if fp32 input);
// row padded to 130 ushorts -> 2-way bank aliasing only (free).
// ---------------------------------------------------------------------------
__global__ __launch_bounds__(192) void proj_kernel(
    const void* __restrict__ x,               // [CIN][HW] bf16 or fp32
    const int* __restrict__ flag,
    const float* __restrict__ wf,             // [3][256][128] fp32
    unsigned short* __restrict__ vbuf,        // [256][HW] bf16 raw
    float* __restrict__ sbuf)                 // [8][HW] fp32
{
    __shared__ unsigned short xs[192][130];
    const int tid = threadIdx.x;              // 0..191
    const int px  = blockIdx.x * 192 + tid;   // one full image row
    const bool f32 = (*flag != 0);

    if (f32) {
        const float* __restrict__ xf = (const float*)x;
        for (int c = 0; c < CIN; c += 2) {
            float a = xf[(c + 0) * HW_ + px];
            float b = xf[(c + 1) * HW_ + px];
            ushort2 p; p.x = f2b(a); p.y = f2b(b);
            *(ushort2*)&xs[tid][c] = p;
        }
    } else {
        const unsigned short* __restrict__ xb = (const unsigned short*)x;
        for (int c = 0; c < CIN; c += 2) {
            ushort2 p;
            p.x = xb[(c + 0) * HW_ + px];
            p.y = xb[(c + 1) * HW_ + px];
            *(ushort2*)&xs[tid][c] = p;
        }
    }
    __syncthreads();

    const int d0 = blockIdx.y * 64;           // wave-uniform d range
    const float* __restrict__ wq = wf + 0 * DK * CIN;
    const float* __restrict__ wk = wf + 1 * DK * CIN;
    const float* __restrict__ wv = wf + 2 * DK * CIN;

    float s0 = 0.f, s1 = 0.f;                 // heads 2*by, 2*by+1

    for (int db = 0; db < 64; db += 4) {
        float aq[4] = {0.f, 0.f, 0.f, 0.f};
        float ak[4] = {0.f, 0.f, 0.f, 0.f};
        float av[4] = {0.f, 0.f, 0.f, 0.f};
        const float* __restrict__ wqr = wq + (d0 + db) * CIN;
        const float* __restrict__ wkr = wk + (d0 + db) * CIN;
        const float* __restrict__ wvr = wv + (d0 + db) * CIN;
        for (int c = 0; c < CIN; c += 2) {
            ushort2 xv2 = *(const ushort2*)&xs[tid][c];
            float x0 = b2f(xv2.x);
            float x1 = b2f(xv2.y);
            #pragma unroll
            for (int u = 0; u < 4; ++u) {
                aq[u] = fmaf(wqr[u * CIN + c],     x0, aq[u]);
                aq[u] = fmaf(wqr[u * CIN + c + 1], x1, aq[u]);
                ak[u] = fmaf(wkr[u * CIN + c],     x0, ak[u]);
                ak[u] = fmaf(wkr[u * CIN + c + 1], x1, ak[u]);
                av[u] = fmaf(wvr[u * CIN + c],     x0, av[u]);
                av[u] = fmaf(wvr[u * CIN + c + 1], x1, av[u]);
            }
        }
        #pragma unroll
        for (int u = 0; u < 4; ++u) {
            float qk = aq[u] * ak[u];
            if (db < 32) s0 += qk; else s1 += qk;   // db uniform -> no divergence
            vbuf[(d0 + db + u) * HW_ + px] = f2b(av[u]);
        }
    }
    const int h0 = blockIdx.y * 2;
    sbuf[h0 * HW_ + px]       = s0;
    sbuf[(h0 + 1) * HW_ + px] = s1;
}

// ---------------------------------------------------------------------------
// Kernel 2: regional softmax + weighted 3x3 gather of v. OOB region slots
// contribute value 0 to the softmax denominator (zero-padded stretch
// semantics) but weight 0 in the v-sum. Output dtype follows input dtype.
// ---------------------------------------------------------------------------
__global__ __launch_bounds__(256) void attn_kernel(
    const unsigned short* __restrict__ vbuf,  // [256][HW] bf16
    const float* __restrict__ sbuf,           // [8][HW]
    const int* __restrict__ flag,
    void* __restrict__ out)                   // [256][HW] bf16 or fp32
{
    const int b    = blockIdx.x;              // 1152 = 8 heads * 144 px-blocks
    const int head = b / 144;
    const int px   = (b % 144) * 256 + threadIdx.x;
    const int y    = px / WI;
    const int xx   = px - y * WI;
    const bool f32 = (*flag != 0);

    const float* __restrict__ Sh = sbuf + head * HW_;

    float w[9];
    int   np[9];
    float m = -1e30f;
    #pragma unroll
    for (int r = 0; r < 9; ++r) {
        int dy = r / 3 - 1, dx = r % 3 - 1;
        int ny = y + dy, nx = xx + dx;
        bool inb = (ny >= 0) && (ny < HT) && (nx >= 0) && (nx < WI);
        int idx = inb ? (ny * WI + nx) : px;  // safe index; weight zeroed below
        np[r] = idx;
        float val = inb ? (Sh[idx] * 0.0625f) : 0.0f;
        w[r] = val;
        m = fmaxf(m, val);
    }
    float wsum = 0.f;
    #pragma unroll
    for (int r = 0; r < 9; ++r) {
        float e = __expf(w[r] - m);
        w[r] = e;
        wsum += e;
    }
    float inv = 1.0f / wsum;
    #pragma unroll
    for (int r = 0; r < 9; ++r) {
        int dy = r / 3 - 1, dx = r % 3 - 1;
        int ny = y + dy, nx = xx + dx;
        bool inb = (ny >= 0) && (ny < HT) && (nx >= 0) && (nx < WI);
        w[r] = inb ? (w[r] * inv) : 0.0f;
    }

    const unsigned short* __restrict__ vb = vbuf + head * DKH * HW_;
    const int obase = head * DKH * HW_;
    for (int ch = 0; ch < DKH; ++ch) {
        const unsigned short* __restrict__ vc = vb + ch * HW_;
        float acc = 0.f;
        #pragma unroll
        for (int r = 0; r < 9; ++r)
            acc = fmaf(w[r], b2f(vc[np[r]]), acc);
        int oi = obase + ch * HW_ + px;
        if (f32) ((float*)out)[oi] = acc;
        else     ((unsigned short*)out)[oi] = f2b(acc);
    }
}

// ---------------------------------------------------------------------------
// Workspace layout:
//   [0, 256)                 flag  : int (dtype detection result)
//   [256, 393472)            wf    : 3*256*128 fp32
//   [393472, 19267840)       vbuf  : 256*36864 bf16
//   [19267840, 20447488)     sbuf  : 8*36864 fp32
// ---------------------------------------------------------------------------
extern "C" void kernel_launch(void* const* d_in, const int* in_sizes, int n_in,
                              void* d_out, int out_size, void* d_ws, size_t ws_size,
                              hipStream_t stream) {
    const void* x  = d_in[0];
    const void* wq = d_in[1];
    const void* wk = d_in[2];
    const void* wv = d_in[3];

    char* ws = (char*)d_ws;
    int*   flag = (int*)ws;
    float* wf   = (float*)(ws + 256);
    unsigned short* vbuf = (unsigned short*)(ws + 393472);
    float* sbuf = (float*)(ws + 19267840);

    detect_kernel<<<1, 256, 0, stream>>>((const unsigned int*)x, flag);
    convw_kernel<<<384, 256, 0, stream>>>(wq, wk, wv, flag, wf);
    proj_kernel<<<dim3(192, 4), 192, 0, stream>>>(x, flag, wf, vbuf, sbuf);
    attn_kernel<<<1152, 256, 0, stream>>>(vbuf, sbuf, flag, (void*)d_out);
}

// Round 3
// 125.785 us; speedup vs baseline: 2.5529x; 2.5529x over previous
//
#include <hip/hip_runtime.h>

// Problem constants
#define HW_   36864      // 192*192
#define WI    192
#define HT    192
#define CIN   128
#define DK    256        // == D_V
#define NH    8
#define DKH   32         // channels per head
// TEMPER = 16 -> scale 1/16 = 0.0625

using short8  = __attribute__((ext_vector_type(8))) short;
using float4_ = __attribute__((ext_vector_type(4))) float;

static __device__ __forceinline__ float b2f(unsigned short u) {
    union { unsigned int i; float f; } x; x.i = ((unsigned int)u) << 16; return x.f;
}
static __device__ __forceinline__ unsigned short f2b(float f) {
    union { float f; unsigned int i; } x; x.f = f;
    unsigned int r = x.i + 0x7FFFu + ((x.i >> 16) & 1u);   // round-nearest-even
    return (unsigned short)(r >> 16);
}

// ---------------------------------------------------------------------------
// Kernel D: input-dtype detection (fp32 vs bf16), as in round 2 (verified).
// ---------------------------------------------------------------------------
__global__ __launch_bounds__(256) void detect_kernel(
    const unsigned int* __restrict__ xw, int* __restrict__ flag)
{
    __shared__ int sh[256];
    int t = threadIdx.x;
    int cnt = 0;
    for (int i = t; i < 4096; i += 256) {
        unsigned int w = xw[i];
        unsigned int e = (w >> 23) & 0xFF;
        if (e >= 96 && e <= 160) cnt++;
    }
    sh[t] = cnt;
    __syncthreads();
    for (int s = 128; s > 0; s >>= 1) {
        if (t < s) sh[t] += sh[t + s];
        __syncthreads();
    }
    if (t == 0) *flag = (sh[0] > 2048) ? 1 : 0;
}

// ---------------------------------------------------------------------------
// Kernel W: weights -> bf16, MFMA-friendly layout wqkv[8][96][128]:
// head h, rows 0-31 = wq[h*32+r], 32-63 = wk, 64-95 = wv.
// ---------------------------------------------------------------------------
__global__ __launch_bounds__(256) void convw_kernel(
    const void* __restrict__ wq,
    const void* __restrict__ wk,
    const void* __restrict__ wv,
    const int* __restrict__ flag,
    unsigned short* __restrict__ wqkv)
{
    int id = blockIdx.x * 256 + threadIdx.x;   // 8*96*128 = 98304
    int h   = id / 12288;
    int rem = id - h * 12288;
    int r   = rem >> 7;
    int c   = rem & 127;
    const void* s = (r < 32) ? wq : ((r < 64) ? wk : wv);
    int si = (h * 32 + (r & 31)) * 128 + c;
    if (*flag) wqkv[id] = f2b(((const float*)s)[si]);
    else       wqkv[id] = ((const unsigned short*)s)[si];
}

// ---------------------------------------------------------------------------
// Kernel X: x [128][HW] (fp32 or bf16) -> xt [HW][128] bf16 (transposed).
// 64px x 128c tile per block through LDS (stride 136 -> 16B-aligned rows).
// ---------------------------------------------------------------------------
__global__ __launch_bounds__(256) void convx_kernel(
    const void* __restrict__ x, const int* __restrict__ flag,
    unsigned short* __restrict__ xt)
{
    __shared__ unsigned short tile[64][136];
    const int px0 = blockIdx.x * 64;
    const int t = threadIdx.x;
    if (*flag) {
        const float* __restrict__ xf = (const float*)x;
        for (int i = 0; i < 32; ++i) {
            int id = i * 256 + t;
            int c = id >> 6, p = id & 63;
            tile[p][c] = f2b(xf[c * HW_ + px0 + p]);
        }
    } else {
        const unsigned short* __restrict__ xb = (const unsigned short*)x;
        for (int i = 0; i < 32; ++i) {
            int id = i * 256 + t;
            int c = id >> 6, p = id & 63;
            tile[p][c] = xb[c * HW_ + px0 + p];
        }
    }
    __syncthreads();
    for (int i = 0; i < 4; ++i) {
        int id = i * 256 + t;                  // 64 rows * 16 chunks
        int row = id >> 4, c8 = id & 15;
        *(short8*)&xt[(px0 + row) * 128 + c8 * 8] =
            *(const short8*)&tile[row][c8 * 8];
    }
}

// ---------------------------------------------------------------------------
// Kernel P: MFMA projection. Block = 256 thr (4 waves), tile = 1 head x 128 px.
// A = wqkv[head] (96x128), B = xt rows (128px x 128c), C = 96x128 fp32 in acc.
// mfma_f32_16x16x32_bf16; wave w owns pixel cols [w*32, w*32+32) (2 N-tiles),
// all 6 M-tiles. Epilogue: S[head][px] = sum_d q*k (lane product + quad
// shuffle-reduce; q/k tiles are row-aligned lane-for-lane), v -> bf16 vbuf.
// LDS stride 136 ushorts: fragment b128 reads 2-way bank-aliased (free).
// ---------------------------------------------------------------------------
__global__ __launch_bounds__(256) void projmm_kernel(
    const unsigned short* __restrict__ xt,     // [HW][128] bf16
    const unsigned short* __restrict__ wqkv,   // [8][96][128] bf16
    unsigned short* __restrict__ vbuf,         // [256][HW] bf16
    float* __restrict__ sbuf)                  // [8][HW] fp32
{
    __shared__ unsigned short As[96 * 136];
    __shared__ unsigned short Bs[128 * 136];
    const int head = blockIdx.x;
    const int px0  = blockIdx.y * 128;
    const int t = threadIdx.x;

    const unsigned short* __restrict__ Ag = wqkv + head * 96 * 128;
    #pragma unroll
    for (int i = 0; i < 6; ++i) {
        int id = i * 256 + t;                  // 96*16 = 1536 16B chunks
        int row = id >> 4, c8 = id & 15;
        *(short8*)&As[row * 136 + c8 * 8] = *(const short8*)&Ag[row * 128 + c8 * 8];
    }
    const unsigned short* __restrict__ Bg = xt + px0 * 128;
    #pragma unroll
    for (int i = 0; i < 8; ++i) {
        int id = i * 256 + t;                  // 128*16 = 2048 chunks
        int row = id >> 4, c8 = id & 15;
        *(short8*)&Bs[row * 136 + c8 * 8] = *(const short8*)&Bg[row * 128 + c8 * 8];
    }
    __syncthreads();

    const int lane = t & 63, wave = t >> 6;
    const int col = lane & 15, quad = lane >> 4;

    // B fragments: B[k][n], lane holds n = col, k = quad*8 + j (j=0..7)
    short8 bfrag[2][4];
    #pragma unroll
    for (int nt = 0; nt < 2; ++nt)
        #pragma unroll
        for (int kt = 0; kt < 4; ++kt) {
            int n = wave * 32 + nt * 16 + col;
            bfrag[nt][kt] = *(const short8*)&Bs[n * 136 + kt * 32 + quad * 8];
        }

    float4_ acc[6][2];
    #pragma unroll
    for (int mt = 0; mt < 6; ++mt)
        #pragma unroll
        for (int nt = 0; nt < 2; ++nt)
            acc[mt][nt] = (float4_){0.f, 0.f, 0.f, 0.f};

    #pragma unroll
    for (int mt = 0; mt < 6; ++mt) {
        #pragma unroll
        for (int kt = 0; kt < 4; ++kt) {
            int m = mt * 16 + col;
            short8 a = *(const short8*)&As[m * 136 + kt * 32 + quad * 8];
            acc[mt][0] = __builtin_amdgcn_mfma_f32_16x16x32_bf16(a, bfrag[0][kt], acc[mt][0], 0, 0, 0);
            acc[mt][1] = __builtin_amdgcn_mfma_f32_16x16x32_bf16(a, bfrag[1][kt], acc[mt][1], 0, 0, 0);
        }
    }

    // Epilogue. C/D layout: col = lane&15 (pixel), row = quad*4 + reg (d).
    #pragma unroll
    for (int nt = 0; nt < 2; ++nt) {
        int px = px0 + wave * 32 + nt * 16 + col;
        float s = 0.f;
        #pragma unroll
        for (int reg = 0; reg < 4; ++reg)
            s += acc[0][nt][reg] * acc[2][nt][reg]
               + acc[1][nt][reg] * acc[3][nt][reg];
        s += __shfl_xor(s, 16, 64);
        s += __shfl_xor(s, 32, 64);
        if (quad == 0) sbuf[head * HW_ + px] = s;
        #pragma unroll
        for (int mt = 4; mt < 6; ++mt)
            #pragma unroll
            for (int reg = 0; reg < 4; ++reg) {
                int d = head * 32 + (mt - 4) * 16 + quad * 4 + reg;
                vbuf[d * HW_ + px] = f2b(acc[mt][nt][reg]);
            }
    }
}

// ---------------------------------------------------------------------------
// Kernel 2: regional softmax + weighted 3x3 gather of v (unchanged, verified).
// ---------------------------------------------------------------------------
__global__ __launch_bounds__(256) void attn_kernel(
    const unsigned short* __restrict__ vbuf,  // [256][HW] bf16
    const float* __restrict__ sbuf,           // [8][HW]
    const int* __restrict__ flag,
    void* __restrict__ out)                   // [256][HW] bf16 or fp32
{
    const int b    = blockIdx.x;              // 1152 = 8 heads * 144 px-blocks
    const int head = b / 144;
    const int px   = (b % 144) * 256 + threadIdx.x;
    const int y    = px / WI;
    const int xx   = px - y * WI;
    const bool f32 = (*flag != 0);

    const float* __restrict__ Sh = sbuf + head * HW_;

    float w[9];
    int   np[9];
    float m = -1e30f;
    #pragma unroll
    for (int r = 0; r < 9; ++r) {
        int dy = r / 3 - 1, dx = r % 3 - 1;
        int ny = y + dy, nx = xx + dx;
        bool inb = (ny >= 0) && (ny < HT) && (nx >= 0) && (nx < WI);
        int idx = inb ? (ny * WI + nx) : px;
        np[r] = idx;
        float val = inb ? (Sh[idx] * 0.0625f) : 0.0f;
        w[r] = val;
        m = fmaxf(m, val);
    }
    float wsum = 0.f;
    #pragma unroll
    for (int r = 0; r < 9; ++r) {
        float e = __expf(w[r] - m);
        w[r] = e;
        wsum += e;
    }
    float inv = 1.0f / wsum;
    #pragma unroll
    for (int r = 0; r < 9; ++r) {
        int dy = r / 3 - 1, dx = r % 3 - 1;
        int ny = y + dy, nx = xx + dx;
        bool inb = (ny >= 0) && (ny < HT) && (nx >= 0) && (nx < WI);
        w[r] = inb ? (w[r] * inv) : 0.0f;
    }

    const unsigned short* __restrict__ vb = vbuf + head * DKH * HW_;
    const int obase = head * DKH * HW_;
    for (int ch = 0; ch < DKH; ++ch) {
        const unsigned short* __restrict__ vc = vb + ch * HW_;
        float acc = 0.f;
        #pragma unroll
        for (int r = 0; r < 9; ++r)
            acc = fmaf(w[r], b2f(vc[np[r]]), acc);
        int oi = obase + ch * HW_ + px;
        if (f32) ((float*)out)[oi] = acc;
        else     ((unsigned short*)out)[oi] = f2b(acc);
    }
}

// ---------------------------------------------------------------------------
// Workspace layout:
//   [0, 256)                     flag
//   [256, 196864)                wqkv : 8*96*128 bf16
//   [196864, 9634048)            xt   : 36864*128 bf16
//   [9634048, 28508416)          vbuf : 256*36864 bf16
//   [28508416, 29688064)         sbuf : 8*36864 fp32     (~29.7 MB total)
// ---------------------------------------------------------------------------
extern "C" void kernel_launch(void* const* d_in, const int* in_sizes, int n_in,
                              void* d_out, int out_size, void* d_ws, size_t ws_size,
                              hipStream_t stream) {
    const void* x  = d_in[0];
    const void* wq = d_in[1];
    const void* wk = d_in[2];
    const void* wv = d_in[3];

    char* ws = (char*)d_ws;
    int*            flag = (int*)ws;
    unsigned short* wqkv = (unsigned short*)(ws + 256);
    unsigned short* xt   = (unsigned short*)(ws + 196864);
    unsigned short* vbuf = (unsigned short*)(ws + 9634048);
    float*          sbuf = (float*)(ws + 28508416);

    detect_kernel<<<1, 256, 0, stream>>>((const unsigned int*)x, flag);
    convw_kernel<<<384, 256, 0, stream>>>(wq, wk, wv, flag, wqkv);
    convx_kernel<<<576, 256, 0, stream>>>(x, flag, xt);
    projmm_kernel<<<dim3(8, 288), 256, 0, stream>>>(xt, wqkv, vbuf, sbuf);
    attn_kernel<<<1152, 256, 0, stream>>>(vbuf, sbuf, flag, (void*)d_out);
}

// Round 4
// 120.285 us; speedup vs baseline: 2.6697x; 1.0457x over previous
//
#include <hip/hip_runtime.h>

// Problem constants
#define HW_   36864      // 192*192
#define WI    192
#define HT    192
#define CIN   128
#define DK    256        // == D_V
#define NH    8
#define DKH   32         // channels per head
// TEMPER = 16 -> scale 1/16 = 0.0625

using short4_ = __attribute__((ext_vector_type(4))) short;
using short8  = __attribute__((ext_vector_type(8))) short;
using float4_ = __attribute__((ext_vector_type(4))) float;

static __device__ __forceinline__ float b2f(unsigned short u) {
    union { unsigned int i; float f; } x; x.i = ((unsigned int)u) << 16; return x.f;
}
static __device__ __forceinline__ unsigned short f2b(float f) {
    union { float f; unsigned int i; } x; x.f = f;
    unsigned int r = x.i + 0x7FFFu + ((x.i >> 16) & 1u);   // round-nearest-even
    return (unsigned short)(r >> 16);
}

// ---------------------------------------------------------------------------
// Kernel D: input-dtype detection (fp32 vs bf16) — verified rounds 2-3.
// ---------------------------------------------------------------------------
__global__ __launch_bounds__(256) void detect_kernel(
    const unsigned int* __restrict__ xw, int* __restrict__ flag)
{
    __shared__ int sh[256];
    int t = threadIdx.x;
    int cnt = 0;
    for (int i = t; i < 4096; i += 256) {
        unsigned int w = xw[i];
        unsigned int e = (w >> 23) & 0xFF;
        if (e >= 96 && e <= 160) cnt++;
    }
    sh[t] = cnt;
    __syncthreads();
    for (int s = 128; s > 0; s >>= 1) {
        if (t < s) sh[t] += sh[t + s];
        __syncthreads();
    }
    if (t == 0) *flag = (sh[0] > 2048) ? 1 : 0;
}

// ---------------------------------------------------------------------------
// Kernel W: weights -> bf16, layout wqkv[8][96][128] (rows 0-31 q, 32-63 k,
// 64-95 v per head) — verified round 3.
// ---------------------------------------------------------------------------
__global__ __launch_bounds__(256) void convw_kernel(
    const void* __restrict__ wq,
    const void* __restrict__ wk,
    const void* __restrict__ wv,
    const int* __restrict__ flag,
    unsigned short* __restrict__ wqkv)
{
    int id = blockIdx.x * 256 + threadIdx.x;   // 8*96*128 = 98304
    int h   = id / 12288;
    int rem = id - h * 12288;
    int r   = rem >> 7;
    int c   = rem & 127;
    const void* s = (r < 32) ? wq : ((r < 64) ? wk : wv);
    int si = (h * 32 + (r & 31)) * 128 + c;
    if (*flag) wqkv[id] = f2b(((const float*)s)[si]);
    else       wqkv[id] = ((const unsigned short*)s)[si];
}

// ---------------------------------------------------------------------------
// Kernel X: x [128][HW] (fp32 or bf16) -> xt [HW][128] bf16 — verified round 3.
// ---------------------------------------------------------------------------
__global__ __launch_bounds__(256) void convx_kernel(
    const void* __restrict__ x, const int* __restrict__ flag,
    unsigned short* __restrict__ xt)
{
    __shared__ unsigned short tile[64][136];
    const int px0 = blockIdx.x * 64;
    const int t = threadIdx.x;
    if (*flag) {
        const float* __restrict__ xf = (const float*)x;
        for (int i = 0; i < 32; ++i) {
            int id = i * 256 + t;
            int c = id >> 6, p = id & 63;
            tile[p][c] = f2b(xf[c * HW_ + px0 + p]);
        }
    } else {
        const unsigned short* __restrict__ xb = (const unsigned short*)x;
        for (int i = 0; i < 32; ++i) {
            int id = i * 256 + t;
            int c = id >> 6, p = id & 63;
            tile[p][c] = xb[c * HW_ + px0 + p];
        }
    }
    __syncthreads();
    for (int i = 0; i < 4; ++i) {
        int id = i * 256 + t;                  // 64 rows * 16 chunks
        int row = id >> 4, c8 = id & 15;
        *(short8*)&xt[(px0 + row) * 128 + c8 * 8] =
            *(const short8*)&tile[row][c8 * 8];
    }
}

// ---------------------------------------------------------------------------
// Kernel P: MFMA projection (compute verified round 3). Epilogue CHANGED:
// v now stored pixel-major vbuf[head][px][32] (two short4 8B stores per lane
// per n-tile) so attn can do 16B coalesced loads.
// ---------------------------------------------------------------------------
__global__ __launch_bounds__(256) void projmm_kernel(
    const unsigned short* __restrict__ xt,     // [HW][128] bf16
    const unsigned short* __restrict__ wqkv,   // [8][96][128] bf16
    unsigned short* __restrict__ vbuf,         // [8][HW][32] bf16
    float* __restrict__ sbuf)                  // [8][HW] fp32
{
    __shared__ unsigned short As[96 * 136];
    __shared__ unsigned short Bs[128 * 136];
    const int head = blockIdx.x;
    const int px0  = blockIdx.y * 128;
    const int t = threadIdx.x;

    const unsigned short* __restrict__ Ag = wqkv + head * 96 * 128;
    #pragma unroll
    for (int i = 0; i < 6; ++i) {
        int id = i * 256 + t;
        int row = id >> 4, c8 = id & 15;
        *(short8*)&As[row * 136 + c8 * 8] = *(const short8*)&Ag[row * 128 + c8 * 8];
    }
    const unsigned short* __restrict__ Bg = xt + px0 * 128;
    #pragma unroll
    for (int i = 0; i < 8; ++i) {
        int id = i * 256 + t;
        int row = id >> 4, c8 = id & 15;
        *(short8*)&Bs[row * 136 + c8 * 8] = *(const short8*)&Bg[row * 128 + c8 * 8];
    }
    __syncthreads();

    const int lane = t & 63, wave = t >> 6;
    const int col = lane & 15, quad = lane >> 4;

    short8 bfrag[2][4];
    #pragma unroll
    for (int nt = 0; nt < 2; ++nt)
        #pragma unroll
        for (int kt = 0; kt < 4; ++kt) {
            int n = wave * 32 + nt * 16 + col;
            bfrag[nt][kt] = *(const short8*)&Bs[n * 136 + kt * 32 + quad * 8];
        }

    float4_ acc[6][2];
    #pragma unroll
    for (int mt = 0; mt < 6; ++mt)
        #pragma unroll
        for (int nt = 0; nt < 2; ++nt)
            acc[mt][nt] = (float4_){0.f, 0.f, 0.f, 0.f};

    #pragma unroll
    for (int mt = 0; mt < 6; ++mt) {
        #pragma unroll
        for (int kt = 0; kt < 4; ++kt) {
            int m = mt * 16 + col;
            short8 a = *(const short8*)&As[m * 136 + kt * 32 + quad * 8];
            acc[mt][0] = __builtin_amdgcn_mfma_f32_16x16x32_bf16(a, bfrag[0][kt], acc[mt][0], 0, 0, 0);
            acc[mt][1] = __builtin_amdgcn_mfma_f32_16x16x32_bf16(a, bfrag[1][kt], acc[mt][1], 0, 0, 0);
        }
    }

    // Epilogue. C/D layout: col = lane&15 (pixel), row = quad*4 + reg (d).
    #pragma unroll
    for (int nt = 0; nt < 2; ++nt) {
        int px = px0 + wave * 32 + nt * 16 + col;
        float s = 0.f;
        #pragma unroll
        for (int reg = 0; reg < 4; ++reg)
            s += acc[0][nt][reg] * acc[2][nt][reg]
               + acc[1][nt][reg] * acc[3][nt][reg];
        s += __shfl_xor(s, 16, 64);
        s += __shfl_xor(s, 32, 64);
        if (quad == 0) sbuf[head * HW_ + px] = s;
        // v channels: dloc = (mt-4)*16 + quad*4 + reg  -> two 8B chunks
        unsigned short* vp = vbuf + ((size_t)head * HW_ + px) * 32;
        short4_ v0, v1;
        #pragma unroll
        for (int reg = 0; reg < 4; ++reg) {
            v0[reg] = (short)f2b(acc[4][nt][reg]);
            v1[reg] = (short)f2b(acc[5][nt][reg]);
        }
        *(short4_*)&vp[quad * 4]      = v0;
        *(short4_*)&vp[16 + quad * 4] = v1;
    }
}

// ---------------------------------------------------------------------------
// Kernel A: regional softmax + weighted 3x3 gather, vectorized.
// Block = 64 px (one chunk of an image row) x 4 ch-groups. Per neighbor one
// coalesced 16B short8 load. d-major output produced via LDS transpose
// (fp32, stride 65 -> <=2-way bank aliasing).
// ---------------------------------------------------------------------------
__global__ __launch_bounds__(256) void attn_kernel(
    const unsigned short* __restrict__ vbuf,  // [8][HW][32] bf16
    const float* __restrict__ sbuf,           // [8][HW]
    const int* __restrict__ flag,
    void* __restrict__ out)                   // [256][HW] bf16 or fp32
{
    __shared__ float tr[32][65];
    const int b    = blockIdx.x;              // 4608 = 576 px-tiles (fast) * 8 heads
    const int tile = b % 576;
    const int head = b / 576;
    const int t    = threadIdx.x;
    const int pxl  = t >> 2;                  // 0..63
    const int cg   = t & 3;                   // channel group (8 ch)
    const int px   = tile * 64 + pxl;         // whole tile in one image row
    const int y    = px / WI;
    const int xx   = px - y * WI;
    const bool f32 = (*flag != 0);

    const float* __restrict__ Sh = sbuf + head * HW_;

    float w[9];
    int   np[9];
    float m = -1e30f;
    #pragma unroll
    for (int r = 0; r < 9; ++r) {
        int dy = r / 3 - 1, dx = r % 3 - 1;
        int ny = y + dy, nx = xx + dx;
        bool inb = (ny >= 0) && (ny < HT) && (nx >= 0) && (nx < WI);
        int idx = inb ? (ny * WI + nx) : px;  // safe index; weight zeroed below
        np[r] = idx;
        float val = inb ? (Sh[idx] * 0.0625f) : 0.0f;
        w[r] = val;
        m = fmaxf(m, val);
    }
    float wsum = 0.f;
    #pragma unroll
    for (int r = 0; r < 9; ++r) {
        float e = __expf(w[r] - m);
        w[r] = e;
        wsum += e;
    }
    float inv = 1.0f / wsum;
    #pragma unroll
    for (int r = 0; r < 9; ++r) {
        int dy = r / 3 - 1, dx = r % 3 - 1;
        int ny = y + dy, nx = xx + dx;
        bool inb = (ny >= 0) && (ny < HT) && (nx >= 0) && (nx < WI);
        w[r] = inb ? (w[r] * inv) : 0.0f;
    }

    const unsigned short* __restrict__ vb = vbuf + (size_t)head * HW_ * 32;
    float acc[8] = {0.f, 0.f, 0.f, 0.f, 0.f, 0.f, 0.f, 0.f};
    #pragma unroll
    for (int r = 0; r < 9; ++r) {
        short8 v8 = *(const short8*)&vb[np[r] * 32 + cg * 8];
        #pragma unroll
        for (int j = 0; j < 8; ++j)
            acc[j] = fmaf(w[r], b2f((unsigned short)v8[j]), acc[j]);
    }
    #pragma unroll
    for (int j = 0; j < 8; ++j)
        tr[cg * 8 + j][pxl] = acc[j];
    __syncthreads();

    // write-out: thread t -> channel ch = t>>3, px chunk c8 = t&7 (8 px)
    const int ch = t >> 3, c8 = t & 7;
    const int px0 = tile * 64;
    const size_t obase = (size_t)(head * DKH + ch) * HW_ + px0 + c8 * 8;
    if (f32) {
        float4_ o0, o1;
        #pragma unroll
        for (int j = 0; j < 4; ++j) {
            o0[j] = tr[ch][c8 * 8 + j];
            o1[j] = tr[ch][c8 * 8 + 4 + j];
        }
        float* o = (float*)out + obase;
        *(float4_*)&o[0] = o0;
        *(float4_*)&o[4] = o1;
    } else {
        short8 o8;
        #pragma unroll
        for (int j = 0; j < 8; ++j)
            o8[j] = (short)f2b(tr[ch][c8 * 8 + j]);
        *(short8*)((unsigned short*)out + obase) = o8;
    }
}

// ---------------------------------------------------------------------------
// Workspace layout:
//   [0, 256)                     flag
//   [256, 196864)                wqkv : 8*96*128 bf16
//   [196864, 9634048)            xt   : 36864*128 bf16
//   [9634048, 28508416)          vbuf : 8*36864*32 bf16 (pixel-major)
//   [28508416, 29688064)         sbuf : 8*36864 fp32
// ---------------------------------------------------------------------------
extern "C" void kernel_launch(void* const* d_in, const int* in_sizes, int n_in,
                              void* d_out, int out_size, void* d_ws, size_t ws_size,
                              hipStream_t stream) {
    const void* x  = d_in[0];
    const void* wq = d_in[1];
    const void* wk = d_in[2];
    const void* wv = d_in[3];

    char* ws = (char*)d_ws;
    int*            flag = (int*)ws;
    unsigned short* wqkv = (unsigned short*)(ws + 256);
    unsigned short* xt   = (unsigned short*)(ws + 196864);
    unsigned short* vbuf = (unsigned short*)(ws + 9634048);
    float*          sbuf = (float*)(ws + 28508416);

    detect_kernel<<<1, 256, 0, stream>>>((const unsigned int*)x, flag);
    convw_kernel<<<384, 256, 0, stream>>>(wq, wk, wv, flag, wqkv);
    convx_kernel<<<576, 256, 0, stream>>>(x, flag, xt);
    projmm_kernel<<<dim3(8, 288), 256, 0, stream>>>(xt, wqkv, vbuf, sbuf);
    attn_kernel<<<4608, 256, 0, stream>>>(vbuf, sbuf, flag, (void*)d_out);
}